// Round 7
// baseline (891.900 us; speedup 1.0000x reference)
//
#include <hip/hip_runtime.h>

// Round 9: A-direct + weights-only LDS + 64x64 block.
// - Convert pass now converts WEIGHTS ONLY (30 MB traffic, ~8 us); input and
//   hidden A-fragments are per-lane slices, loaded straight from the original
//   fp32 arrays and converted in-register with the same RNE f2bf (bit-identical
//   to the old two-pass numerics).
// - gru block 64x64, 4 waves 2Mx2N, wave tile 32x32 -> acc shrinks 160->80
//   regs, making reg-staging register-feasible: 80 acc + 32 A-staging + 16
//   frags + ~50 addr/misc ~= 200 < 256/wave cap at __launch_bounds__(256,2)
//   (pool measured ~512/SIMD; R4/R5 spilled because 160-reg acc + staging
//   blew the cap).
// - LDS holds only W tiles: 3 x 20480 B triple-buffer (61 KB, 2 blocks/CU).
//   W prefetched 2 tiles ahead (global_load_lds), A 1 tile ahead in regs.
//   Per-tile schedule: ONE s_waitcnt vmcnt(5) + ONE s_barrier (R1 had 2
//   barriers); in-flight queue steady at 18 (W+A of two future tiles), never
//   drained in the main loop.
// - Slot-XOR swizzle kept on W image (conflicts measured 0), setprio kept.

#define BM 64
#define BN 64
#define BK 32

typedef __attribute__((ext_vector_type(8))) short          bf16x8;
typedef __attribute__((ext_vector_type(8))) unsigned short u16x8;
typedef __attribute__((ext_vector_type(4))) float          f32x4;

__device__ __forceinline__ unsigned short f2bf(float f) {
    union { float f; unsigned u; } v; v.f = f;
    unsigned r = v.u + 0x7FFFu + ((v.u >> 16) & 1u);  // RNE
    return (unsigned short)(r >> 16);
}

// ---- Pass 1: weights-only fp32 -> bf16 into ws ----
// ws layout (elements): [g*1048576) W_g for g=0..4 (gates r_i,r_h,z_i,n_i,n_h)
// 5*1048576 elements = 655360 vec8 units = 2560 blocks * 256.
__global__ __launch_bounds__(256) void convert_w(
    const float* __restrict__ w0, const float* __restrict__ w1,
    const float* __restrict__ w2, const float* __restrict__ w3,
    const float* __restrict__ w4, unsigned short* __restrict__ ws)
{
    const int e = (blockIdx.x * 256 + threadIdx.x) * 8;
    const int g = e >> 20;
    const int within = e & 1048575;
    const float* w = (g == 0) ? w0 : (g == 1) ? w1 : (g == 2) ? w2 : (g == 3) ? w3 : w4;
    const float4 a = *reinterpret_cast<const float4*>(w + within);
    const float4 b = *reinterpret_cast<const float4*>(w + within + 4);
    u16x8 o;
    o[0] = f2bf(a.x); o[1] = f2bf(a.y); o[2] = f2bf(a.z); o[3] = f2bf(a.w);
    o[4] = f2bf(b.x); o[5] = f2bf(b.y); o[6] = f2bf(b.z); o[7] = f2bf(b.w);
    *reinterpret_cast<u16x8*>(ws + e) = o;
}

// ---- async 16B global->LDS ----
__device__ __forceinline__ void async16(const void* g, void* l) {
    __builtin_amdgcn_global_load_lds(
        (const __attribute__((address_space(1))) unsigned int*)g,
        (__attribute__((address_space(3))) unsigned int*)l, 16, 0, 0);
}

#define CFENCE() asm volatile("" ::: "memory")
#define MFMA16(a, b, c) __builtin_amdgcn_mfma_f32_16x16x32_bf16((a), (b), (c), 0, 0, 0)

// ---- Pass 2: fused GRU ----
// LDS per W buffer: sW[5][64 rows][64 B] = 20480 B; 1280 slots = 256 thr x 5.
// Slot swizzle: physical 16B slot p of row n holds logical chunk p^((n>>1)&3)
// (pre-swizzled global source; same involution via sq on reads; measured 0
// bank conflicts).
__global__ __launch_bounds__(256, 2) void gru_fused(
    const unsigned short* __restrict__ wsW,  // bf16 weights [5][1024][1024]
    const float* __restrict__ input,         // fp32 [16384][1024]
    const float* __restrict__ hidden,        // fp32 [16384][1024]
    const float* __restrict__ b_ri, const float* __restrict__ b_rh,
    const float* __restrict__ b_zi, const float* __restrict__ b_ni,
    const float* __restrict__ b_nh,
    float* __restrict__ out)
{
    const int H = 1024;
    const int BH = 16384 * 1024;

    __shared__ __align__(16) unsigned char sW[3][20480];   // 61440 B -> 2 blocks/CU

    const int tid  = threadIdx.x;
    const int wave = tid >> 6;
    const int lane = tid & 63;
    const int quad = lane >> 4;
    const int l16  = lane & 15;
    const int sq   = quad ^ ((l16 >> 1) & 3);   // swizzled 16B slot for B reads
    const int wm   = wave >> 1;                 // 0..1 (M position)
    const int wn   = wave & 1;                  // 0..1 (N position)

    const int row0 = blockIdx.y * BM;
    const int col0 = blockIdx.x * BN;

    // W staging: slot s = j*256+tid (j=0..4): g = s>>8, tt = s&255,
    // n = tt>>2 (weight output-row), physical chunk tt&3 holds logical
    // chunk (tt&3)^((n>>1)&3).
    unsigned srcoff[5];
    #pragma unroll
    for (int j = 0; j < 5; ++j) {
        const int s = j * 256 + tid;
        const int g = s >> 8;
        const int tt = s & 255;
        const int n = tt >> 2;
        const int c = (tt & 3) ^ ((n >> 1) & 3);
        srcoff[j] = (unsigned)g * 1048576u + (unsigned)(col0 + n) * 1024u + (unsigned)c * 8u;
    }
    const int ldsoff = tid * 16;

    #define STAGEW(k0, dst) do {                                               \
        _Pragma("unroll")                                                      \
        for (int j = 0; j < 5; ++j)                                            \
            async16(wsW + srcoff[j] + (unsigned)(k0), (dst) + j * 4096 + ldsoff); \
    } while (0)

    // A-fragment base pointers: lane reads fp32 input[r][k0 + quad*8 .. +8]
    // as two float4 (per mi, per matrix). Each 16-row group covers 128B/row
    // contiguously across its two loads -> cache-line efficient.
    const float* pIn[2];
    const float* pHid[2];
    #pragma unroll
    for (int mi = 0; mi < 2; ++mi) {
        const int r = row0 + wm * 32 + mi * 16 + l16;
        pIn [mi] = input  + (long long)r * 1024 + quad * 8;
        pHid[mi] = hidden + (long long)r * 1024 + quad * 8;
    }

    float4 sI[2][2], sH[2][2];      // fp32 staging (A of next tile in flight)
    bf16x8 aIn[2], aHid[2];         // converted frags of current tile

    #define LOADA(k0) do {                                                     \
        _Pragma("unroll")                                                      \
        for (int mi = 0; mi < 2; ++mi) {                                       \
            sI[mi][0] = *reinterpret_cast<const float4*>(pIn [mi] + (k0));     \
            sI[mi][1] = *reinterpret_cast<const float4*>(pIn [mi] + (k0) + 4); \
            sH[mi][0] = *reinterpret_cast<const float4*>(pHid[mi] + (k0));     \
            sH[mi][1] = *reinterpret_cast<const float4*>(pHid[mi] + (k0) + 4); \
        }                                                                      \
    } while (0)

    #define CVTA() do {                                                        \
        _Pragma("unroll")                                                      \
        for (int mi = 0; mi < 2; ++mi) {                                       \
            u16x8 oi, oh;                                                      \
            oi[0] = f2bf(sI[mi][0].x); oi[1] = f2bf(sI[mi][0].y);              \
            oi[2] = f2bf(sI[mi][0].z); oi[3] = f2bf(sI[mi][0].w);              \
            oi[4] = f2bf(sI[mi][1].x); oi[5] = f2bf(sI[mi][1].y);              \
            oi[6] = f2bf(sI[mi][1].z); oi[7] = f2bf(sI[mi][1].w);              \
            oh[0] = f2bf(sH[mi][0].x); oh[1] = f2bf(sH[mi][0].y);              \
            oh[2] = f2bf(sH[mi][0].z); oh[3] = f2bf(sH[mi][0].w);              \
            oh[4] = f2bf(sH[mi][1].x); oh[5] = f2bf(sH[mi][1].y);              \
            oh[6] = f2bf(sH[mi][1].z); oh[7] = f2bf(sH[mi][1].w);              \
            aIn [mi] = *reinterpret_cast<bf16x8*>(&oi);                        \
            aHid[mi] = *reinterpret_cast<bf16x8*>(&oh);                        \
        }                                                                      \
    } while (0)

    f32x4 acc[5][2][2];
    #pragma unroll
    for (int g = 0; g < 5; ++g)
        #pragma unroll
        for (int mi = 0; mi < 2; ++mi)
            #pragma unroll
            for (int ni = 0; ni < 2; ++ni)
                acc[g][mi][ni] = (f32x4){0.f, 0.f, 0.f, 0.f};

    #define COMPUTE(sb) do {                                                   \
        __builtin_amdgcn_s_setprio(1);                                         \
        _Pragma("unroll")                                                      \
        for (int g = 0; g < 5; ++g) {                                          \
            _Pragma("unroll")                                                  \
            for (int ni = 0; ni < 2; ++ni) {                                   \
                const int n = wn * 32 + ni * 16 + l16;                         \
                const bf16x8 bb = *reinterpret_cast<const bf16x8*>(            \
                    (sb) + g * 4096 + n * 64 + sq * 16);                       \
                _Pragma("unroll")                                              \
                for (int mi = 0; mi < 2; ++mi) {                               \
                    acc[g][mi][ni] = MFMA16(                                   \
                        (g == 1 || g == 4) ? aHid[mi] : aIn[mi],               \
                        bb, acc[g][mi][ni]);                                   \
                }                                                              \
            }                                                                  \
        }                                                                      \
        __builtin_amdgcn_s_setprio(0);                                         \
    } while (0)

    unsigned char* bA = &sW[0][0];
    unsigned char* bB = &sW[1][0];
    unsigned char* bC = &sW[2][0];

    // ---- prologue: queue (oldest->newest) = [A(0):8, W(0):5, W(1):5] ----
    LOADA(0);           CFENCE();
    STAGEW(0,  bA);     CFENCE();
    STAGEW(BK, bB);     CFENCE();

    // Steady iter t (t = 0..30): entry queue = [W(t):5, A(t):8, W(t+1):5].
    //   vmcnt(5): drains the 13 oldest = W(t)+A(t); W(t+1) stays in flight.
    //   convert A(t) -> frags; issue A(t+1) into freed staging regs;
    //   barrier (all waves' W(t) confirmed); stage W(t+2) into the buffer
    //   consumed at t-1; compute(t) from bA; rotate buffers.
    #pragma unroll 1
    for (int t = 0; t < 31; ++t) {
        asm volatile("s_waitcnt vmcnt(5)" ::: "memory");
        CVTA();
        LOADA((t + 1) * BK);
        CFENCE(); __builtin_amdgcn_s_barrier(); CFENCE();
        if (t < 30) STAGEW((t + 2) * BK, bC);
        COMPUTE(bA);
        unsigned char* tmp = bA; bA = bB; bB = bC; bC = tmp;
    }
    // ---- tail t=31: queue = [W(31):5, A(31):8] ----
    asm volatile("s_waitcnt vmcnt(0)" ::: "memory");
    CVTA();
    CFENCE(); __builtin_amdgcn_s_barrier(); CFENCE();
    COMPUTE(bA);

    // Epilogue: C/D layout row = quad*4 + r4, col = l16 per 16x16 tile.
    #pragma unroll
    for (int ni = 0; ni < 2; ++ni) {
        const int gcol = col0 + wn * 32 + ni * 16 + l16;
        const float bri = b_ri[gcol], brh = b_rh[gcol], bzi = b_zi[gcol];
        const float bni = b_ni[gcol], bnh = b_nh[gcol];
        #pragma unroll
        for (int mi = 0; mi < 2; ++mi) {
            #pragma unroll
            for (int r4 = 0; r4 < 4; ++r4) {
                const int grow = row0 + wm * 32 + mi * 16 + quad * 4 + r4;
                const float g_ri = acc[0][mi][ni][r4];
                const float g_rh = acc[1][mi][ni][r4];
                const float g_zi = acc[2][mi][ni][r4];
                const float g_ni = acc[3][mi][ni][r4];
                const float g_nh = acc[4][mi][ni][r4];
                const float rh = g_rh + brh;                  // shared by r and z (reference bug kept)
                const float rr = 1.f / (1.f + __expf(-(g_ri + bri + rh)));
                const float zz = 1.f / (1.f + __expf(-(g_zi + bzi + rh)));
                const float nn = tanhf(g_ni + bni + rr * (g_nh + bnh));
                const float h  = hidden[(long long)grow * H + gcol];
                const float o  = (1.f - zz) * nn + zz * h;
                out[(long long)grow * H + gcol]      = o;
                out[BH + (long long)grow * H + gcol] = o;
            }
        }
    }
}

extern "C" void kernel_launch(void* const* d_in, const int* in_sizes, int n_in,
                              void* d_out, int out_size, void* d_ws, size_t ws_size,
                              hipStream_t stream) {
    const float* input  = (const float*)d_in[0];
    const float* hidden = (const float*)d_in[1];
    const float* W_ri = (const float*)d_in[2];
    const float* b_ri = (const float*)d_in[3];
    const float* W_rh = (const float*)d_in[4];
    const float* b_rh = (const float*)d_in[5];
    const float* W_zi = (const float*)d_in[6];
    const float* b_zi = (const float*)d_in[7];
    // d_in[8], d_in[9] = W_z_h, b_z_h: dead per the reference's bug (z uses r_h)
    const float* W_ni = (const float*)d_in[10];
    const float* b_ni = (const float*)d_in[11];
    const float* W_nh = (const float*)d_in[12];
    const float* b_nh = (const float*)d_in[13];
    float* out = (float*)d_out;
    unsigned short* ws = (unsigned short*)d_ws;

    // gate order in ws: 0=r_i 1=r_h 2=z_i 3=n_i 4=n_h
    convert_w<<<2560, 256, 0, stream>>>(W_ri, W_rh, W_zi, W_ni, W_nh, ws);

    dim3 grid(1024 / BN, 16384 / BM);  // (16, 256)
    gru_fused<<<grid, 256, 0, stream>>>(ws, input, hidden,
                                        b_ri, b_rh, b_zi, b_ni, b_nh, out);
}

// Round 8
// 544.058 us; speedup vs baseline: 1.6393x; 1.6393x over previous
//
#include <hip/hip_runtime.h>

// Round 10: R6 structure at doubled occupancy. gru_fused is R6's kernel
// (128x64 block, BK=32, LDS dbuf 2x36864, global_load_lds staging, counted
// vmcnt, XOR slot swizzle, setprio, 2 barriers/tile) but with 512 threads /
// 8 waves arranged 4Mx2N (wave tile 32x32): acc 160->80 regs/wave, and
// __launch_bounds__(512,4) caps 128 regs/wave (R7 measured 104 for this wave
// tile -> fits), giving 16 waves/CU vs R6's register-capped 8. Mechanism: R6
// is latency-bound (all pipes ~25%); doubling resident waves fills the
// barrier/ds-read dead time. A stays in the bf16 ws image via global_load_lds
// (R7 lesson: direct fp32 A 1-tile-ahead exposes full HBM latency, 9% MfmaUtil).
// convert_bf16: one-shot 18944-block version (best known).

#define BM 128
#define BN 64
#define BK 32
#define TILE_BYTES 36864

typedef __attribute__((ext_vector_type(8))) short          bf16x8;
typedef __attribute__((ext_vector_type(8))) unsigned short u16x8;
typedef __attribute__((ext_vector_type(4))) float          f32x4;

__device__ __forceinline__ unsigned short f2bf(float f) {
    union { float f; unsigned u; } v; v.f = f;
    unsigned r = v.u + 0x7FFFu + ((v.u >> 16) & 1u);  // RNE
    return (unsigned short)(r >> 16);
}

// ---- Pass 1: fp32 -> bf16 conversion into ws (one vec8 per thread) ----
// ws layout (elements): [0) input 16777216 | [16777216) hidden 16777216 |
//                       [33554432 + g*1048576) W_g for g=0..4
// Total vec8 = 4,849,664 = 18944 blocks * 256.
__global__ __launch_bounds__(256) void convert_bf16(
    const float* __restrict__ in0, const float* __restrict__ in1,
    const float* __restrict__ w0, const float* __restrict__ w1,
    const float* __restrict__ w2, const float* __restrict__ w3,
    const float* __restrict__ w4, unsigned short* __restrict__ ws)
{
    const long long e = ((long long)blockIdx.x * 256 + threadIdx.x) * 8;
    const float* src;
    if (e < 16777216LL) {
        src = in0 + e;
    } else if (e < 33554432LL) {
        src = in1 + (e - 16777216LL);
    } else {
        const long long t = e - 33554432LL;
        const int g = (int)(t >> 20);
        const long long within = t & 1048575LL;
        const float* w = (g == 0) ? w0 : (g == 1) ? w1 : (g == 2) ? w2 : (g == 3) ? w3 : w4;
        src = w + within;
    }
    const float4 a = *reinterpret_cast<const float4*>(src);
    const float4 b = *reinterpret_cast<const float4*>(src + 4);
    u16x8 o;
    o[0] = f2bf(a.x); o[1] = f2bf(a.y); o[2] = f2bf(a.z); o[3] = f2bf(a.w);
    o[4] = f2bf(b.x); o[5] = f2bf(b.y); o[6] = f2bf(b.z); o[7] = f2bf(b.w);
    *reinterpret_cast<u16x8*>(ws + e) = o;
}

// ---- async 16B global->LDS ----
__device__ __forceinline__ void async16(const void* g, void* l) {
    __builtin_amdgcn_global_load_lds(
        (const __attribute__((address_space(1))) unsigned int*)g,
        (__attribute__((address_space(3))) unsigned int*)l, 16, 0, 0);
}

#define CFENCE() asm volatile("" ::: "memory")
#define MFMA16(a, b, c) __builtin_amdgcn_mfma_f32_16x16x32_bf16((a), (b), (c), 0, 0, 0)

// ---- Pass 2: fused GRU, double-buffered + swizzled, 8 waves ----
// Per-tile LDS image (bf16, linear dest as global_load_lds requires):
//   [0, 8192)       sIn  [128 rows][64 B]   (4 x 16B slots per row)
//   [8192, 16384)   sHid [128 rows][64 B]
//   [16384, 36864)  sW[5][64 rows][64 B]
// Slot swizzle: logical 16B slot c of row r stored at physical c ^ ((r>>1)&3)
// (pre-swizzled GLOBAL source at staging; same involution via sq on reads;
// measured SQ_LDS_BANK_CONFLICT = 0).
// 2304 slots / 512 threads: j=0..3 all threads (s = j*512+tid), j=4 tid<256.
// Waves 4Mx2N: wave (wm,wn) owns rows [wm*32,+32) x cols [wn*32,+32).
__global__ __launch_bounds__(512, 4) void gru_fused(
    const unsigned short* __restrict__ bf,   // ws: bf16 image
    const float* __restrict__ hidden,        // fp32, for epilogue z*h
    const float* __restrict__ b_ri, const float* __restrict__ b_rh,
    const float* __restrict__ b_zi, const float* __restrict__ b_ni,
    const float* __restrict__ b_nh,
    float* __restrict__ out)
{
    const int H = 1024, K = 1024;
    const int BH = 16384 * 1024;

    __shared__ __align__(16) unsigned char sBuf[2][TILE_BYTES];

    const int tid  = threadIdx.x;
    const int wave = tid >> 6;
    const int lane = tid & 63;
    const int quad = lane >> 4;
    const int l16  = lane & 15;
    const int sq   = quad ^ ((l16 >> 1) & 3);   // swizzled 16B slot for reads
    const int wm   = wave >> 1;                 // 0..3 (M position)
    const int wn   = wave & 1;                  // 0..1 (N position)

    const int row0 = blockIdx.y * BM;
    const int col0 = blockIdx.x * BN;

    const unsigned short* inB  = bf;               // input  bf16 [16384][1024]
    const unsigned short* hidB = bf + 16777216;    // hidden bf16 [16384][1024]
    const unsigned short* wB   = bf + 33554432;    // W bf16 [5][1024][1024]

    // Per-slot global base pointers (k0=0, source slot pre-swizzled) + LDS offs.
    const unsigned short* srcbase[5];
    int ldsoff[5];
    #pragma unroll
    for (int j = 0; j < 5; ++j) {
        if (j < 4 || tid < 256) {
            const int s = j * 512 + tid;
            ldsoff[j] = s * 16;
            if (s < 512) {                       // input tile
                const int r = s >> 2;
                const int c = (s & 3) ^ ((r >> 1) & 3);
                srcbase[j] = inB + (long long)(row0 + r) * K + c * 8;
            } else if (s < 1024) {               // hidden tile
                const int r = (s - 512) >> 2;
                const int c = (s & 3) ^ ((r >> 1) & 3);
                srcbase[j] = hidB + (long long)(row0 + r) * K + c * 8;
            } else {                             // weight tiles
                const int t = s - 1024;
                const int g = t >> 8;
                const int tt = t & 255;
                const int n = tt >> 2;
                const int c = (tt & 3) ^ ((n >> 1) & 3);
                srcbase[j] = wB + (long long)g * 1048576 + (long long)(col0 + n) * K + c * 8;
            }
        }
    }

    f32x4 acc[5][2][2];
    #pragma unroll
    for (int g = 0; g < 5; ++g)
        #pragma unroll
        for (int mi = 0; mi < 2; ++mi)
            #pragma unroll
            for (int ni = 0; ni < 2; ++ni)
                acc[g][mi][ni] = (f32x4){0.f, 0.f, 0.f, 0.f};

    unsigned char* b0 = &sBuf[0][0];
    unsigned char* b1 = &sBuf[1][0];

    auto stage = [&](int k0, unsigned char* dst) {
        #pragma unroll
        for (int j = 0; j < 5; ++j)
            if (j < 4 || tid < 256)
                async16(srcbase[j] + k0, dst + ldsoff[j]);
    };

    // Per-wave counted wait: waves 0-3 issue 5 loads/tile, waves 4-7 issue 4.
    // Steady state: tile t's loads are the oldest; tile t+1's (5 or 4) newer.
    #define WAIT_N() do {                                                      \
        if (tid < 256) asm volatile("s_waitcnt vmcnt(5)" ::: "memory");        \
        else           asm volatile("s_waitcnt vmcnt(4)" ::: "memory");        \
    } while (0)

    auto compute = [&](const unsigned char* sb) {
        bf16x8 aIn[2], aHid[2];
        #pragma unroll
        for (int mi = 0; mi < 2; ++mi) {
            const int r = wm * 32 + mi * 16 + l16;
            aIn [mi] = *reinterpret_cast<const bf16x8*>(sb + r * 64 + sq * 16);
            aHid[mi] = *reinterpret_cast<const bf16x8*>(sb + 8192 + r * 64 + sq * 16);
        }
        __builtin_amdgcn_s_setprio(1);
        #pragma unroll
        for (int g = 0; g < 5; ++g) {
            #pragma unroll
            for (int ni = 0; ni < 2; ++ni) {
                const int n = wn * 32 + ni * 16 + l16;
                const bf16x8 b = *reinterpret_cast<const bf16x8*>(
                    sb + 16384 + g * 4096 + n * 64 + sq * 16);
                #pragma unroll
                for (int mi = 0; mi < 2; ++mi) {
                    const bf16x8 a = (g == 1 || g == 4) ? aHid[mi] : aIn[mi];
                    acc[g][mi][ni] = MFMA16(a, b, acc[g][mi][ni]);
                }
            }
        }
        __builtin_amdgcn_s_setprio(0);
    };

    // ---- pipelined K loop: 32 tiles, 1-deep prefetch, counted vmcnt ----
    // tile t lives in buf[t&1]. Per step: issue stage(t+1) -> wait OWN tile-t
    // loads -> barrier (=> ALL waves' tile-t loads done) -> compute(t) ->
    // barrier (buf[t] may be restaged at t+2).
    stage(0, b0);
    #pragma unroll 1
    for (int i = 0; i < 15; ++i) {
        const int k2 = i * 2 * BK;
        stage(k2 + BK, b1);
        WAIT_N();
        __builtin_amdgcn_s_barrier(); CFENCE();
        compute(b0); CFENCE();
        __builtin_amdgcn_s_barrier(); CFENCE();

        stage(k2 + 2 * BK, b0);
        WAIT_N();
        __builtin_amdgcn_s_barrier(); CFENCE();
        compute(b1); CFENCE();
        __builtin_amdgcn_s_barrier(); CFENCE();
    }
    // tiles 30 (in b0) and 31
    stage(31 * BK, b1);
    WAIT_N();
    __builtin_amdgcn_s_barrier(); CFENCE();
    compute(b0); CFENCE();
    __builtin_amdgcn_s_barrier(); CFENCE();
    asm volatile("s_waitcnt vmcnt(0)" ::: "memory");
    __builtin_amdgcn_s_barrier(); CFENCE();
    compute(b1);

    // Epilogue: C/D layout row = quad*4 + r4, col = l16 per 16x16 tile.
    #pragma unroll
    for (int ni = 0; ni < 2; ++ni) {
        const int gcol = col0 + wn * 32 + ni * 16 + l16;
        const float bri = b_ri[gcol], brh = b_rh[gcol], bzi = b_zi[gcol];
        const float bni = b_ni[gcol], bnh = b_nh[gcol];
        #pragma unroll
        for (int mi = 0; mi < 2; ++mi) {
            #pragma unroll
            for (int r4 = 0; r4 < 4; ++r4) {
                const int grow = row0 + wm * 32 + mi * 16 + quad * 4 + r4;
                const float g_ri = acc[0][mi][ni][r4];
                const float g_rh = acc[1][mi][ni][r4];
                const float g_zi = acc[2][mi][ni][r4];
                const float g_ni = acc[3][mi][ni][r4];
                const float g_nh = acc[4][mi][ni][r4];
                const float rh = g_rh + brh;                  // shared by r and z (reference bug kept)
                const float rr = 1.f / (1.f + __expf(-(g_ri + bri + rh)));
                const float zz = 1.f / (1.f + __expf(-(g_zi + bzi + rh)));
                const float nn = tanhf(g_ni + bni + rr * (g_nh + bnh));
                const float h  = hidden[(long long)grow * H + gcol];
                const float o  = (1.f - zz) * nn + zz * h;
                out[(long long)grow * H + gcol]      = o;
                out[BH + (long long)grow * H + gcol] = o;
            }
        }
    }
}

extern "C" void kernel_launch(void* const* d_in, const int* in_sizes, int n_in,
                              void* d_out, int out_size, void* d_ws, size_t ws_size,
                              hipStream_t stream) {
    const float* input  = (const float*)d_in[0];
    const float* hidden = (const float*)d_in[1];
    const float* W_ri = (const float*)d_in[2];
    const float* b_ri = (const float*)d_in[3];
    const float* W_rh = (const float*)d_in[4];
    const float* b_rh = (const float*)d_in[5];
    const float* W_zi = (const float*)d_in[6];
    const float* b_zi = (const float*)d_in[7];
    // d_in[8], d_in[9] = W_z_h, b_z_h: dead per the reference's bug (z uses r_h)
    const float* W_ni = (const float*)d_in[10];
    const float* b_ni = (const float*)d_in[11];
    const float* W_nh = (const float*)d_in[12];
    const float* b_nh = (const float*)d_in[13];
    float* out = (float*)d_out;
    unsigned short* ws = (unsigned short*)d_ws;

    // gate order in ws: 0=r_i 1=r_h 2=z_i 3=n_i 4=n_h
    convert_bf16<<<18944, 256, 0, stream>>>(input, hidden, W_ri, W_rh, W_zi, W_ni, W_nh, ws);

    dim3 grid(1024 / BN, 16384 / BM);  // (16, 128)
    gru_fused<<<grid, 512, 0, stream>>>(ws, hidden, b_ri, b_rh, b_zi, b_ni, b_nh, out);
}

// Round 9
// 523.562 us; speedup vs baseline: 1.7035x; 1.0391x over previous
//
#include <hip/hip_runtime.h>

// Round 11: R8 + register diet to fit the 128-reg/wave cap without spilling.
// R8 proved the occupancy mechanism (22->39%) but spilled ~10 regs (VGPR 64 +
// WRITE_SIZE +92MB scratch signature) because addressing overhead (5x 64-bit
// srcbase ptrs + ldsoff[5] = ~15 regs) pushed the wave over 128. Diet:
//   1) srcbase pointers -> 5x 32-bit element offsets from the single bf base
//      (saves 5 regs, enables saddr-form global_load_lds),
//   2) ldsoff[] -> j*8192 immediate + tid*16 (saves 5 regs).
// Budget: acc 80 + frags 16 + addr ~6 + misc ~15 = ~117-125 <= 128 ->
// 2 blocks/CU, 16 waves/CU, no spill. All else identical to R8 (512 thr,
// 8 waves 4Mx2N, wave tile 32x32, LDS dbuf 2x36864, counted vmcnt(5)/(4),
// 2 barriers/tile, XOR slot swizzle (conflicts=0), setprio, one-shot convert).
// Primary check: WRITE_SIZE ~198MB (spill gone). If spill persists, the
// 5-gate register wall is fundamental -> revert to R6 and declare plateau.

#define BM 128
#define BN 64
#define BK 32
#define TILE_BYTES 36864

typedef __attribute__((ext_vector_type(8))) short          bf16x8;
typedef __attribute__((ext_vector_type(8))) unsigned short u16x8;
typedef __attribute__((ext_vector_type(4))) float          f32x4;

__device__ __forceinline__ unsigned short f2bf(float f) {
    union { float f; unsigned u; } v; v.f = f;
    unsigned r = v.u + 0x7FFFu + ((v.u >> 16) & 1u);  // RNE
    return (unsigned short)(r >> 16);
}

// ---- Pass 1: fp32 -> bf16 conversion into ws (one vec8 per thread) ----
// ws layout (elements): [0) input 16777216 | [16777216) hidden 16777216 |
//                       [33554432 + g*1048576) W_g for g=0..4
// Total vec8 = 4,849,664 = 18944 blocks * 256.
__global__ __launch_bounds__(256) void convert_bf16(
    const float* __restrict__ in0, const float* __restrict__ in1,
    const float* __restrict__ w0, const float* __restrict__ w1,
    const float* __restrict__ w2, const float* __restrict__ w3,
    const float* __restrict__ w4, unsigned short* __restrict__ ws)
{
    const long long e = ((long long)blockIdx.x * 256 + threadIdx.x) * 8;
    const float* src;
    if (e < 16777216LL) {
        src = in0 + e;
    } else if (e < 33554432LL) {
        src = in1 + (e - 16777216LL);
    } else {
        const long long t = e - 33554432LL;
        const int g = (int)(t >> 20);
        const long long within = t & 1048575LL;
        const float* w = (g == 0) ? w0 : (g == 1) ? w1 : (g == 2) ? w2 : (g == 3) ? w3 : w4;
        src = w + within;
    }
    const float4 a = *reinterpret_cast<const float4*>(src);
    const float4 b = *reinterpret_cast<const float4*>(src + 4);
    u16x8 o;
    o[0] = f2bf(a.x); o[1] = f2bf(a.y); o[2] = f2bf(a.z); o[3] = f2bf(a.w);
    o[4] = f2bf(b.x); o[5] = f2bf(b.y); o[6] = f2bf(b.z); o[7] = f2bf(b.w);
    *reinterpret_cast<u16x8*>(ws + e) = o;
}

// ---- async 16B global->LDS ----
__device__ __forceinline__ void async16(const void* g, void* l) {
    __builtin_amdgcn_global_load_lds(
        (const __attribute__((address_space(1))) unsigned int*)g,
        (__attribute__((address_space(3))) unsigned int*)l, 16, 0, 0);
}

#define CFENCE() asm volatile("" ::: "memory")
#define MFMA16(a, b, c) __builtin_amdgcn_mfma_f32_16x16x32_bf16((a), (b), (c), 0, 0, 0)

// ---- Pass 2: fused GRU, double-buffered + swizzled, 8 waves ----
// Per-tile LDS image (bf16, linear dest as global_load_lds requires):
//   [0, 8192)       sIn  [128 rows][64 B]   (4 x 16B slots per row)
//   [8192, 16384)   sHid [128 rows][64 B]
//   [16384, 36864)  sW[5][64 rows][64 B]
// Slot swizzle: logical 16B slot c of row r stored at physical c ^ ((r>>1)&3)
// (pre-swizzled GLOBAL source at staging; same involution via sq on reads;
// measured SQ_LDS_BANK_CONFLICT = 0).
// 2304 slots / 512 threads: j=0..3 all threads (s = j*512+tid), j=4 tid<256.
// Waves 4Mx2N: wave (wm,wn) owns rows [wm*32,+32) x cols [wn*32,+32).
__global__ __launch_bounds__(512, 4) void gru_fused(
    const unsigned short* __restrict__ bf,   // ws: bf16 image
    const float* __restrict__ hidden,        // fp32, for epilogue z*h
    const float* __restrict__ b_ri, const float* __restrict__ b_rh,
    const float* __restrict__ b_zi, const float* __restrict__ b_ni,
    const float* __restrict__ b_nh,
    float* __restrict__ out)
{
    const int H = 1024, K = 1024;
    const int BH = 16384 * 1024;

    __shared__ __align__(16) unsigned char sBuf[2][TILE_BYTES];

    const int tid  = threadIdx.x;
    const int wave = tid >> 6;
    const int lane = tid & 63;
    const int quad = lane >> 4;
    const int l16  = lane & 15;
    const int sq   = quad ^ ((l16 >> 1) & 3);   // swizzled 16B slot for reads
    const int wm   = wave >> 1;                 // 0..3 (M position)
    const int wn   = wave & 1;                  // 0..1 (N position)
    const int tid16 = tid * 16;                 // LDS byte offset within j-block

    const int row0 = blockIdx.y * BM;
    const int col0 = blockIdx.x * BN;

    // Per-slot 32-bit ELEMENT offsets into bf (k0=0, source pre-swizzled).
    // Slot s = j*512 + tid; LDS dest byte = j*8192 + tid*16 (computed inline).
    unsigned srcoff[5];
    #pragma unroll
    for (int j = 0; j < 5; ++j) {
        if (j < 4 || tid < 256) {
            const int s = j * 512 + tid;
            if (s < 512) {                       // input tile: 4 slots per row
                const int r = s >> 2;
                const int c = (s & 3) ^ ((r >> 1) & 3);
                srcoff[j] = (unsigned)((row0 + r) * K + c * 8);
            } else if (s < 1024) {               // hidden tile
                const int r = (s - 512) >> 2;
                const int c = (s & 3) ^ ((r >> 1) & 3);
                srcoff[j] = 16777216u + (unsigned)((row0 + r) * K + c * 8);
            } else {                             // weight tiles
                const int t = s - 1024;
                const int g = t >> 8;
                const int tt = t & 255;
                const int n = tt >> 2;
                const int c = (tt & 3) ^ ((n >> 1) & 3);
                srcoff[j] = 33554432u + (unsigned)g * 1048576u
                          + (unsigned)(col0 + n) * 1024u + (unsigned)c * 8u;
            }
        }
    }

    f32x4 acc[5][2][2];
    #pragma unroll
    for (int g = 0; g < 5; ++g)
        #pragma unroll
        for (int mi = 0; mi < 2; ++mi)
            #pragma unroll
            for (int ni = 0; ni < 2; ++ni)
                acc[g][mi][ni] = (f32x4){0.f, 0.f, 0.f, 0.f};

    unsigned char* b0 = &sBuf[0][0];
    unsigned char* b1 = &sBuf[1][0];

    auto stage = [&](int k0, unsigned char* dst) {
        #pragma unroll
        for (int j = 0; j < 5; ++j)
            if (j < 4 || tid < 256)
                async16(bf + srcoff[j] + (unsigned)k0, dst + j * 8192 + tid16);
    };

    // Per-wave counted wait: waves 0-3 issue 5 loads/tile, waves 4-7 issue 4.
    // Steady state: tile t's loads are oldest; tile t+1's (5 or 4) newer.
    #define WAIT_N() do {                                                      \
        if (tid < 256) asm volatile("s_waitcnt vmcnt(5)" ::: "memory");        \
        else           asm volatile("s_waitcnt vmcnt(4)" ::: "memory");        \
    } while (0)

    auto compute = [&](const unsigned char* sb) {
        bf16x8 aIn[2], aHid[2];
        #pragma unroll
        for (int mi = 0; mi < 2; ++mi) {
            const int r = wm * 32 + mi * 16 + l16;
            aIn [mi] = *reinterpret_cast<const bf16x8*>(sb + r * 64 + sq * 16);
            aHid[mi] = *reinterpret_cast<const bf16x8*>(sb + 8192 + r * 64 + sq * 16);
        }
        __builtin_amdgcn_s_setprio(1);
        #pragma unroll
        for (int g = 0; g < 5; ++g) {
            #pragma unroll
            for (int ni = 0; ni < 2; ++ni) {
                const int n = wn * 32 + ni * 16 + l16;
                const bf16x8 b = *reinterpret_cast<const bf16x8*>(
                    sb + 16384 + g * 4096 + n * 64 + sq * 16);
                #pragma unroll
                for (int mi = 0; mi < 2; ++mi) {
                    const bf16x8 a = (g == 1 || g == 4) ? aHid[mi] : aIn[mi];
                    acc[g][mi][ni] = MFMA16(a, b, acc[g][mi][ni]);
                }
            }
        }
        __builtin_amdgcn_s_setprio(0);
    };

    // ---- pipelined K loop: 32 tiles, 1-deep prefetch, counted vmcnt ----
    // tile t lives in buf[t&1]. Per step: issue stage(t+1) -> wait OWN tile-t
    // loads -> barrier (=> ALL waves' tile-t loads done) -> compute(t) ->
    // barrier (buf[t] may be restaged at t+2).
    stage(0, b0);
    #pragma unroll 1
    for (int i = 0; i < 15; ++i) {
        const int k2 = i * 2 * BK;
        stage(k2 + BK, b1);
        WAIT_N();
        __builtin_amdgcn_s_barrier(); CFENCE();
        compute(b0); CFENCE();
        __builtin_amdgcn_s_barrier(); CFENCE();

        stage(k2 + 2 * BK, b0);
        WAIT_N();
        __builtin_amdgcn_s_barrier(); CFENCE();
        compute(b1); CFENCE();
        __builtin_amdgcn_s_barrier(); CFENCE();
    }
    // tiles 30 (in b0) and 31
    stage(31 * BK, b1);
    WAIT_N();
    __builtin_amdgcn_s_barrier(); CFENCE();
    compute(b0); CFENCE();
    __builtin_amdgcn_s_barrier(); CFENCE();
    asm volatile("s_waitcnt vmcnt(0)" ::: "memory");
    __builtin_amdgcn_s_barrier(); CFENCE();
    compute(b1);

    // Epilogue: C/D layout row = quad*4 + r4, col = l16 per 16x16 tile.
    #pragma unroll
    for (int ni = 0; ni < 2; ++ni) {
        const int gcol = col0 + wn * 32 + ni * 16 + l16;
        const float bri = b_ri[gcol], brh = b_rh[gcol], bzi = b_zi[gcol];
        const float bni = b_ni[gcol], bnh = b_nh[gcol];
        #pragma unroll
        for (int mi = 0; mi < 2; ++mi) {
            #pragma unroll
            for (int r4 = 0; r4 < 4; ++r4) {
                const int grow = row0 + wm * 32 + mi * 16 + quad * 4 + r4;
                const float g_ri = acc[0][mi][ni][r4];
                const float g_rh = acc[1][mi][ni][r4];
                const float g_zi = acc[2][mi][ni][r4];
                const float g_ni = acc[3][mi][ni][r4];
                const float g_nh = acc[4][mi][ni][r4];
                const float rh = g_rh + brh;                  // shared by r and z (reference bug kept)
                const float rr = 1.f / (1.f + __expf(-(g_ri + bri + rh)));
                const float zz = 1.f / (1.f + __expf(-(g_zi + bzi + rh)));
                const float nn = tanhf(g_ni + bni + rr * (g_nh + bnh));
                const float h  = hidden[(long long)grow * H + gcol];
                const float o  = (1.f - zz) * nn + zz * h;
                out[(long long)grow * H + gcol]      = o;
                out[BH + (long long)grow * H + gcol] = o;
            }
        }
    }
}

extern "C" void kernel_launch(void* const* d_in, const int* in_sizes, int n_in,
                              void* d_out, int out_size, void* d_ws, size_t ws_size,
                              hipStream_t stream) {
    const float* input  = (const float*)d_in[0];
    const float* hidden = (const float*)d_in[1];
    const float* W_ri = (const float*)d_in[2];
    const float* b_ri = (const float*)d_in[3];
    const float* W_rh = (const float*)d_in[4];
    const float* b_rh = (const float*)d_in[5];
    const float* W_zi = (const float*)d_in[6];
    const float* b_zi = (const float*)d_in[7];
    // d_in[8], d_in[9] = W_z_h, b_z_h: dead per the reference's bug (z uses r_h)
    const float* W_ni = (const float*)d_in[10];
    const float* b_ni = (const float*)d_in[11];
    const float* W_nh = (const float*)d_in[12];
    const float* b_nh = (const float*)d_in[13];
    float* out = (float*)d_out;
    unsigned short* ws = (unsigned short*)d_ws;

    // gate order in ws: 0=r_i 1=r_h 2=z_i 3=n_i 4=n_h
    convert_bf16<<<18944, 256, 0, stream>>>(input, hidden, W_ri, W_rh, W_zi, W_ni, W_nh, ws);

    dim3 grid(1024 / BN, 16384 / BM);  // (16, 128)
    gru_fused<<<grid, 512, 0, stream>>>(ws, hidden, b_ri, b_rh, b_zi, b_ni, b_nh, out);
}

// Round 10
// 488.543 us; speedup vs baseline: 1.8256x; 1.0717x over previous
//
#include <hip/hip_runtime.h>

// Round 12: R6 (best, 488.8us) + two evidence-backed edits, register-neutral:
//  1) wave layout 1Mx4 -> 2Mx2N (wave tile 64x32): per-tile ds_read_b128
//     24 -> 18 (-25% LDS port traffic, the top modeled per-CU floor ~190us).
//     Indexing ported verbatim from R2 (verified pass) with its XCD swizzle
//     DELETED (the swizzle added +280MB FETCH and masked this layout's gain).
//  2) s_setprio removed: structure-conditional technique, measured null-to-
//     negative on lockstep 2-barrier GEMM structures (m190).
// Everything else R6-verbatim: one-shot convert (18944 blocks), LDS dbuf
// 2x36864, global_load_lds staging (zero staging regs; mandatory given the
// 160-reg acc under the 256-reg/wave cap), counted vmcnt(9), 2 barriers/tile,
// XOR slot swizzle (conflicts measured 0), (256,2) launch bounds.
// Falsified this session: occupancy x2 (R8/R9: MfmaUtil flat 25%), phase-split
// at 1 blk/CU (R3), XCD swizzle (R2 FETCH x1.8), reg-staged A (R5/R7 spill /
// latency). Decision rule: total >= ~490 -> plateau confirmed, R6-class final.

#define BM 128
#define BN 64
#define BK 32
#define TILE_BYTES 36864

typedef __attribute__((ext_vector_type(8))) short          bf16x8;
typedef __attribute__((ext_vector_type(8))) unsigned short u16x8;
typedef __attribute__((ext_vector_type(4))) float          f32x4;

__device__ __forceinline__ unsigned short f2bf(float f) {
    union { float f; unsigned u; } v; v.f = f;
    unsigned r = v.u + 0x7FFFu + ((v.u >> 16) & 1u);  // RNE
    return (unsigned short)(r >> 16);
}

// ---- Pass 1: fp32 -> bf16 conversion into ws (one vec8 per thread) ----
// ws layout (elements): [0) input 16777216 | [16777216) hidden 16777216 |
//                       [33554432 + g*1048576) W_g for g=0..4
// Total vec8 = 4,849,664 = 18944 blocks * 256.
__global__ __launch_bounds__(256) void convert_bf16(
    const float* __restrict__ in0, const float* __restrict__ in1,
    const float* __restrict__ w0, const float* __restrict__ w1,
    const float* __restrict__ w2, const float* __restrict__ w3,
    const float* __restrict__ w4, unsigned short* __restrict__ ws)
{
    const long long e = ((long long)blockIdx.x * 256 + threadIdx.x) * 8;
    const float* src;
    if (e < 16777216LL) {
        src = in0 + e;
    } else if (e < 33554432LL) {
        src = in1 + (e - 16777216LL);
    } else {
        const long long t = e - 33554432LL;
        const int g = (int)(t >> 20);
        const long long within = t & 1048575LL;
        const float* w = (g == 0) ? w0 : (g == 1) ? w1 : (g == 2) ? w2 : (g == 3) ? w3 : w4;
        src = w + within;
    }
    const float4 a = *reinterpret_cast<const float4*>(src);
    const float4 b = *reinterpret_cast<const float4*>(src + 4);
    u16x8 o;
    o[0] = f2bf(a.x); o[1] = f2bf(a.y); o[2] = f2bf(a.z); o[3] = f2bf(a.w);
    o[4] = f2bf(b.x); o[5] = f2bf(b.y); o[6] = f2bf(b.z); o[7] = f2bf(b.w);
    *reinterpret_cast<u16x8*>(ws + e) = o;
}

// ---- async 16B global->LDS ----
__device__ __forceinline__ void async16(const void* g, void* l) {
    __builtin_amdgcn_global_load_lds(
        (const __attribute__((address_space(1))) unsigned int*)g,
        (__attribute__((address_space(3))) unsigned int*)l, 16, 0, 0);
}

// compiler-level memory fence (no instruction) to bracket raw s_barrier so
// ds_reads cannot be hoisted above / sunk below it
#define CFENCE() asm volatile("" ::: "memory")

// ---- Pass 2: fused GRU, double-buffered + swizzled, waves 2Mx2N ----
// Per-tile LDS image (bf16, linear dest as global_load_lds requires):
//   [0, 8192)       sIn  [128 rows][64 B]   (4 x 16B slots per row)
//   [8192, 16384)   sHid [128 rows][64 B]
//   [16384, 36864)  sW[5][64 rows][64 B]
// Slot swizzle: logical 16B slot c of row r stored at physical c ^ ((r>>1)&3)
// (applied on the GLOBAL source at staging; same involution via sq on reads).
// Measured SQ_LDS_BANK_CONFLICT = 0.
// Waves 2Mx2N: wave (wm,wn) owns rows [wm*64,+64) x cols [wn*32,+32):
// per-tile ds_read_b128 = 8 A + 10 B = 18 (1Mx4 layout was 24).
__global__ __launch_bounds__(256, 2) void gru_fused(
    const unsigned short* __restrict__ bf,   // ws: bf16 image
    const float* __restrict__ hidden,        // fp32, for epilogue z*h
    const float* __restrict__ b_ri, const float* __restrict__ b_rh,
    const float* __restrict__ b_zi, const float* __restrict__ b_ni,
    const float* __restrict__ b_nh,
    float* __restrict__ out)
{
    const int H = 1024, K = 1024;
    const int BH = 16384 * 1024;

    __shared__ __align__(16) unsigned char sBuf[2][TILE_BYTES];

    const int tid  = threadIdx.x;
    const int wave = tid >> 6;
    const int lane = tid & 63;
    const int quad = lane >> 4;
    const int l16  = lane & 15;
    const int sq   = quad ^ ((l16 >> 1) & 3);   // swizzled 16B slot for reads
    const int wm   = wave >> 1;                 // 0..1 (M position)
    const int wn   = wave & 1;                  // 0..1 (N position)

    const int row0 = blockIdx.y * BM;
    const int col0 = blockIdx.x * BN;

    const unsigned short* inB  = bf;               // input  bf16 [16384][1024]
    const unsigned short* hidB = bf + 16777216;    // hidden bf16 [16384][1024]
    const unsigned short* wB   = bf + 33554432;    // W bf16 [5][1024][1024]

    // Per-slot global base pointers (k0=0, source slot pre-swizzled) + LDS offs.
    const unsigned short* srcbase[9];
    int ldsoff[9];
    #pragma unroll
    for (int j = 0; j < 9; ++j) {
        const int s = (j * 4 + wave) * 64 + lane;
        ldsoff[j] = s * 16;
        if (s < 512) {                       // input tile
            const int r = s >> 2;
            const int c = (s & 3) ^ ((r >> 1) & 3);
            srcbase[j] = inB + (long long)(row0 + r) * K + c * 8;
        } else if (s < 1024) {               // hidden tile
            const int r = (s - 512) >> 2;
            const int c = (s & 3) ^ ((r >> 1) & 3);
            srcbase[j] = hidB + (long long)(row0 + r) * K + c * 8;
        } else {                             // weight tiles
            const int t = s - 1024;
            const int g = t >> 8;
            const int tt = t & 255;
            const int n = tt >> 2;
            const int c = (tt & 3) ^ ((n >> 1) & 3);
            srcbase[j] = wB + (long long)g * 1048576 + (long long)(col0 + n) * K + c * 8;
        }
    }

    f32x4 acc[5][4][2];
    #pragma unroll
    for (int g = 0; g < 5; ++g)
        #pragma unroll
        for (int mi = 0; mi < 4; ++mi)
            #pragma unroll
            for (int ni = 0; ni < 2; ++ni)
                acc[g][mi][ni] = (f32x4){0.f, 0.f, 0.f, 0.f};

    unsigned char* b0 = &sBuf[0][0];
    unsigned char* b1 = &sBuf[1][0];

    auto stage = [&](int k0, unsigned char* dst) {
        #pragma unroll
        for (int j = 0; j < 9; ++j)
            async16(srcbase[j] + k0, dst + ldsoff[j]);
    };

    auto compute = [&](const unsigned char* sb) {
        bf16x8 aIn[4], aHid[4];
        #pragma unroll
        for (int mi = 0; mi < 4; ++mi) {
            const int r = wm * 64 + mi * 16 + l16;
            aIn [mi] = *reinterpret_cast<const bf16x8*>(sb + r * 64 + sq * 16);
            aHid[mi] = *reinterpret_cast<const bf16x8*>(sb + 8192 + r * 64 + sq * 16);
        }
        #pragma unroll
        for (int g = 0; g < 5; ++g) {
            #pragma unroll
            for (int ni = 0; ni < 2; ++ni) {
                const int n = wn * 32 + ni * 16 + l16;
                const bf16x8 b = *reinterpret_cast<const bf16x8*>(
                    sb + 16384 + g * 4096 + n * 64 + sq * 16);
                #pragma unroll
                for (int mi = 0; mi < 4; ++mi) {
                    const bf16x8 a = (g == 1 || g == 4) ? aHid[mi] : aIn[mi];
                    acc[g][mi][ni] = __builtin_amdgcn_mfma_f32_16x16x32_bf16(a, b, acc[g][mi][ni], 0, 0, 0);
                }
            }
        }
    };

    // ---- pipelined K loop: 32 tiles, 1-deep prefetch, counted vmcnt ----
    // tile t lives in buf[t&1]. Per step: issue stage(t+1) -> wait OWN tile-t
    // loads (vmcnt(9): 9 newer in flight) -> barrier (=> ALL waves' tile-t
    // loads done) -> compute(t) -> barrier (buf[t] may be restaged at t+2).
    stage(0, b0);
    #pragma unroll 1
    for (int i = 0; i < 15; ++i) {
        const int k2 = i * 2 * BK;
        stage(k2 + BK, b1);
        asm volatile("s_waitcnt vmcnt(9)" ::: "memory");
        __builtin_amdgcn_s_barrier(); CFENCE();
        compute(b0); CFENCE();
        __builtin_amdgcn_s_barrier(); CFENCE();

        stage(k2 + 2 * BK, b0);
        asm volatile("s_waitcnt vmcnt(9)" ::: "memory");
        __builtin_amdgcn_s_barrier(); CFENCE();
        compute(b1); CFENCE();
        __builtin_amdgcn_s_barrier(); CFENCE();
    }
    // tiles 30 (in b0) and 31
    stage(31 * BK, b1);
    asm volatile("s_waitcnt vmcnt(9)" ::: "memory");
    __builtin_amdgcn_s_barrier(); CFENCE();
    compute(b0); CFENCE();
    __builtin_amdgcn_s_barrier(); CFENCE();
    asm volatile("s_waitcnt vmcnt(0)" ::: "memory");
    __builtin_amdgcn_s_barrier(); CFENCE();
    compute(b1);

    // Epilogue: C/D layout row = quad*4 + r4, col = l16 per 16x16 tile.
    #pragma unroll
    for (int ni = 0; ni < 2; ++ni) {
        const int gcol = col0 + wn * 32 + ni * 16 + l16;
        const float bri = b_ri[gcol], brh = b_rh[gcol], bzi = b_zi[gcol];
        const float bni = b_ni[gcol], bnh = b_nh[gcol];
        #pragma unroll
        for (int mi = 0; mi < 4; ++mi) {
            #pragma unroll
            for (int r4 = 0; r4 < 4; ++r4) {
                const int grow = row0 + wm * 64 + mi * 16 + quad * 4 + r4;
                const float g_ri = acc[0][mi][ni][r4];
                const float g_rh = acc[1][mi][ni][r4];
                const float g_zi = acc[2][mi][ni][r4];
                const float g_ni = acc[3][mi][ni][r4];
                const float g_nh = acc[4][mi][ni][r4];
                const float rh = g_rh + brh;                  // shared by r and z (reference bug kept)
                const float rr = 1.f / (1.f + __expf(-(g_ri + bri + rh)));
                const float zz = 1.f / (1.f + __expf(-(g_zi + bzi + rh)));
                const float nn = tanhf(g_ni + bni + rr * (g_nh + bnh));
                const float h  = hidden[(long long)grow * H + gcol];
                const float o  = (1.f - zz) * nn + zz * h;
                out[(long long)grow * H + gcol]      = o;
                out[BH + (long long)grow * H + gcol] = o;
            }
        }
    }
}

extern "C" void kernel_launch(void* const* d_in, const int* in_sizes, int n_in,
                              void* d_out, int out_size, void* d_ws, size_t ws_size,
                              hipStream_t stream) {
    const float* input  = (const float*)d_in[0];
    const float* hidden = (const float*)d_in[1];
    const float* W_ri = (const float*)d_in[2];
    const float* b_ri = (const float*)d_in[3];
    const float* W_rh = (const float*)d_in[4];
    const float* b_rh = (const float*)d_in[5];
    const float* W_zi = (const float*)d_in[6];
    const float* b_zi = (const float*)d_in[7];
    // d_in[8], d_in[9] = W_z_h, b_z_h: dead per the reference's bug (z uses r_h)
    const float* W_ni = (const float*)d_in[10];
    const float* b_ni = (const float*)d_in[11];
    const float* W_nh = (const float*)d_in[12];
    const float* b_nh = (const float*)d_in[13];
    float* out = (float*)d_out;
    unsigned short* ws = (unsigned short*)d_ws;

    // gate order in ws: 0=r_i 1=r_h 2=z_i 3=n_i 4=n_h
    convert_bf16<<<18944, 256, 0, stream>>>(input, hidden, W_ri, W_rh, W_zi, W_ni, W_nh, ws);

    dim3 grid(1024 / BN, 16384 / BM);  // (16, 128)
    gru_fused<<<grid, 256, 0, stream>>>(ws, hidden, b_ri, b_rh, b_zi, b_ni, b_nh, out);
}